// Round 16
// baseline (1106.473 us; speedup 1.0000x reference)
//
#include <hip/hip_runtime.h>
#include <math.h>

#define DD 64
typedef unsigned short ushort_t;
typedef __attribute__((ext_vector_type(8))) short bf16x8;
typedef __attribute__((ext_vector_type(4))) float f32x4;

#define GEPW 16
#define TPW 16

__device__ __forceinline__ float silu_f(float x) {
    return x / (1.0f + __expf(-x));
}

__device__ __forceinline__ unsigned f32_to_bf16_rne(float x) {
    unsigned u = __float_as_uint(x);
    unsigned r = ((u >> 16) & 1u) + 0x7fffu;
    return (u + r) >> 16;
}

__device__ __forceinline__ float bf16_to_f32(ushort_t v) {
    return __uint_as_float(((unsigned)v) << 16);
}

__device__ __forceinline__ float2 bf2_lo_hi(unsigned u) {
    return make_float2(__uint_as_float(u << 16), __uint_as_float(u & 0xffff0000u));
}

__device__ __forceinline__ void gload_lds4(const void* gsrc, void* lds_base) {
    __builtin_amdgcn_global_load_lds(
        (const __attribute__((address_space(1))) void*)gsrc,
        (__attribute__((address_space(3))) void*)lds_base,
        4, 0, 0);
}

#define RFL(x) __builtin_amdgcn_readfirstlane(x)

// ---------------- sort chain ----------------
__global__ __launch_bounds__(256) void hist_kernel(const int* __restrict__ eidx,
                                                   int* __restrict__ counts, int E) {
    int i = blockIdx.x * 256 + threadIdx.x;
    if (i < E) atomicAdd(&counts[((const int2*)eidx)[i].x], 1);
}

__global__ __launch_bounds__(1024) void scan_kernel(const int* __restrict__ counts,
                                                    int* __restrict__ cursor, int N) {
    __shared__ int part[1024];
    int tid = threadIdx.x;
    int CH = (N + 1023) / 1024;
    int lo = tid * CH, hi = lo + CH; if (hi > N) hi = N; if (lo > N) lo = N;
    int s = 0;
    for (int i = lo; i < hi; ++i) s += counts[i];
    part[tid] = s;
    __syncthreads();
    for (int d = 1; d < 1024; d <<= 1) {
        int v = (tid >= d) ? part[tid - d] : 0;
        __syncthreads();
        part[tid] += v;
        __syncthreads();
    }
    int run = (tid == 0) ? 0 : part[tid - 1];
    for (int i = lo; i < hi; ++i) {
        cursor[i] = run;
        run += counts[i];
    }
}

// ---------------- fused prep: scatter2 | node_transform(bf16 C,D) | node_vector
__global__ __launch_bounds__(256) void fused_prep_kernel(
    const int* __restrict__ eidx, const float* __restrict__ pos,
    int* __restrict__ cursor, int2* __restrict__ eperm, float* __restrict__ relg,
    const float* __restrict__ ns, const float* __restrict__ nc,
    const float* __restrict__ Ws1, const float* __restrict__ Wc1,
    ushort_t* __restrict__ Abf, ushort_t* __restrict__ Bbf,
    ushort_t* __restrict__ Cbf, ushort_t* __restrict__ Dmbf, float* __restrict__ out1,
    const float* __restrict__ nv, const float* __restrict__ WV, const float* __restrict__ bV,
    float* __restrict__ out0, float* __restrict__ out2,
    unsigned* __restrict__ nv01p, ushort_t* __restrict__ nv2bf,
    int N, int E, int sblocks)
{
    __shared__ __align__(16) char smem[69632];
    int tid = threadIdx.x;
    int bx = blockIdx.x;

    if (bx < sblocks) {
        // -------- scatter2 --------
        int i = bx * 256 + tid;
        if (i < E) {
            int2 p = ((const int2*)eidx)[i];
            int dst = atomicAdd(&cursor[p.x], 1);
            eperm[dst] = p;
            relg[3 * (size_t)dst + 0] = pos[(size_t)p.y * 3 + 0] - pos[(size_t)p.x * 3 + 0];
            relg[3 * (size_t)dst + 1] = pos[(size_t)p.y * 3 + 1] - pos[(size_t)p.x * 3 + 1];
            relg[3 * (size_t)dst + 2] = pos[(size_t)p.y * 3 + 2] - pos[(size_t)p.x * 3 + 2];
        }
        return;
    }
    if (bx < sblocks + 2048) {
        // -------- node_transform --------
        int blk = bx - sblocks;
        float* w1   = (float*)smem;                  // 32 KiB
        float* wc1s = (float*)(smem + 32768);        // 32 KiB
        float* xs   = (float*)(smem + 65536);        // 2 KiB
        float* ys   = (float*)(smem + 67584);        // 2 KiB
        for (int i = tid; i < 128 * 64 / 4; i += 256) {
            ((float4*)w1)[i]   = ((const float4*)Ws1)[i];
            ((float4*)wc1s)[i] = ((const float4*)Wc1)[i];
        }
        __syncthreads();
        int wave = tid >> 6, lane = tid & 63;
        for (int nb = blk * 8; nb < N; nb += 2048 * 8) {
            int n0 = nb + wave * 2;
            #pragma unroll
            for (int s = 0; s < 2; ++s) {
                int n = n0 + s;
                float xv = 0.f, yv = 0.f;
                if (n < N) { xv = ns[(size_t)n * DD + lane]; yv = nc[(size_t)n * DD + lane]; }
                xs[(wave * 2 + s) * 64 + lane] = xv;
                ys[(wave * 2 + s) * 64 + lane] = yv;
            }
            float aA[2] = {0.f, 0.f}, aB[2] = {0.f, 0.f}, aC[2] = {0.f, 0.f}, aD[2] = {0.f, 0.f};
            for (int k = 0; k < 64; ++k) {
                float wa  = w1[k * 64 + lane];
                float wb  = w1[(64 + k) * 64 + lane];
                float wca = wc1s[k * 64 + lane];
                float wcb = wc1s[(64 + k) * 64 + lane];
                #pragma unroll
                for (int s = 0; s < 2; ++s) {
                    float xk = xs[(wave * 2 + s) * 64 + k];
                    float yk = ys[(wave * 2 + s) * 64 + k];
                    aA[s] += xk * wa;  aB[s] += xk * wb;
                    aC[s] += yk * wca; aD[s] += yk * wcb;
                }
            }
            #pragma unroll
            for (int s = 0; s < 2; ++s) {
                int n = n0 + s;
                if (n < N) {
                    Abf[(size_t)n * DD + lane]  = (ushort_t)f32_to_bf16_rne(aA[s]);
                    Bbf[(size_t)n * DD + lane]  = (ushort_t)f32_to_bf16_rne(aB[s]);
                    Cbf[(size_t)n * DD + lane]  = (ushort_t)f32_to_bf16_rne(aC[s]);
                    Dmbf[(size_t)n * DD + lane] = (ushort_t)f32_to_bf16_rne(aD[s]);
                    out1[(size_t)n * DD + lane] = ys[(wave * 2 + s) * 64 + lane];
                }
            }
            __syncthreads();
        }
        return;
    }
    // -------- node_vector --------
    {
        int blk = bx - sblocks - 2048;
        float* wv = (float*)smem;                    // 16 KiB
        float* vs = (float*)(smem + 16384);          // 6 KiB
        for (int i = tid; i < 64 * 64 / 4; i += 256)
            ((float4*)wv)[i] = ((const float4*)WV)[i];
        __syncthreads();
        int wave = tid >> 6, lane = tid & 63;
        float bVj = bV[lane];
        for (int nb = blk * 8; nb < N; nb += 2048 * 8) {
            int n0 = nb + wave * 2;
            #pragma unroll
            for (int s = 0; s < 2; ++s) {
                int n = n0 + s;
                float v0 = 0.f, v1 = 0.f, v2 = 0.f;
                if (n < N) {
                    v0 = nv[((size_t)n * 3 + 0) * DD + lane];
                    v1 = nv[((size_t)n * 3 + 1) * DD + lane];
                    v2 = nv[((size_t)n * 3 + 2) * DD + lane];
                }
                vs[((wave * 2 + s) * 3 + 0) * 64 + lane] = v0;
                vs[((wave * 2 + s) * 3 + 1) * 64 + lane] = v1;
                vs[((wave * 2 + s) * 3 + 2) * 64 + lane] = v2;
            }
            float a0[2], a1[2], a2[2];
            #pragma unroll
            for (int s = 0; s < 2; ++s) { a0[s] = bVj; a1[s] = bVj; a2[s] = bVj; }
            for (int k = 0; k < 64; ++k) {
                float w = wv[k * 64 + lane];
                #pragma unroll
                for (int s = 0; s < 2; ++s) {
                    a0[s] += vs[((wave * 2 + s) * 3 + 0) * 64 + k] * w;
                    a1[s] += vs[((wave * 2 + s) * 3 + 1) * 64 + k] * w;
                    a2[s] += vs[((wave * 2 + s) * 3 + 2) * 64 + k] * w;
                }
            }
            #pragma unroll
            for (int s = 0; s < 2; ++s) {
                int n = n0 + s;
                if (n < N) {
                    float norm = sqrtf(a0[s] * a0[s] + a1[s] * a1[s] + a2[s] * a2[s]);
                    float x = ns[(size_t)n * DD + lane];
                    out0[(size_t)n * DD + lane] = x * (1.f + norm);
                    float v0 = vs[((wave * 2 + s) * 3 + 0) * 64 + lane];
                    float v1 = vs[((wave * 2 + s) * 3 + 1) * 64 + lane];
                    float v2 = vs[((wave * 2 + s) * 3 + 2) * 64 + lane];
                    out2[((size_t)n * 3 + 0) * DD + lane] = v0;
                    out2[((size_t)n * 3 + 1) * DD + lane] = v1;
                    out2[((size_t)n * 3 + 2) * DD + lane] = v2;
                    nv01p[(size_t)n * DD + lane] = f32_to_bf16_rne(v0) | (f32_to_bf16_rne(v1) << 16);
                    nv2bf[(size_t)n * DD + lane] = (ushort_t)f32_to_bf16_rne(v2);
                }
            }
            __syncthreads();
        }
    }
}

// ---------------- Kernel 2: edges — round-14 standalone body
__global__ __launch_bounds__(256) void edge_kernel(
    const ushort_t* __restrict__ Abf, const ushort_t* __restrict__ Bbf,
    const unsigned* __restrict__ nv01p, const ushort_t* __restrict__ nv2bf,
    const float* __restrict__ relg, const int2* __restrict__ eperm,
    const float* __restrict__ bs1, const float* __restrict__ Ws2, const float* __restrict__ bs2,
    float* __restrict__ out0, float* __restrict__ out2, int E)
{
    __shared__ __align__(16) unsigned w2frag[12 * 2 * 64 * 4];   // 24 KiB
    __shared__ __align__(16) ushort_t stAB[4][GEPW][128];        // 16 KiB
    __shared__ __align__(16) ushort_t stNV2[4][GEPW / 2][132];   // 8.25 KiB
    __shared__ __align__(16) float    relL[4][64];               // 1 KiB
    int tid = threadIdx.x;
    for (int i = tid; i < 12 * 2 * 64; i += 256) {
        int t  = i >> 7;
        int kk = (i >> 6) & 1;
        int l  = i & 63;
        int k0 = kk * 32 + (l >> 4) * 8;
        int col = t * 16 + (l & 15);
        #pragma unroll
        for (int jp = 0; jp < 4; ++jp) {
            float a = Ws2[(size_t)(k0 + 2 * jp) * 192 + col];
            float b = Ws2[(size_t)(k0 + 2 * jp + 1) * 192 + col];
            w2frag[i * 4 + jp] = f32_to_bf16_rne(a) | (f32_to_bf16_rne(b) << 16);
        }
    }
    __syncthreads();
    int wave = RFL(tid >> 6);
    int lane = tid & 63;
    float b1 = bs1[lane];
    float b2v_t[4], b2e_t[4], b2s_t[4];
    #pragma unroll
    for (int t = 0; t < 4; ++t) {
        b2v_t[t] = bs2[t * 16 + (lane & 15)];
        b2e_t[t] = bs2[64 + t * 16 + (lane & 15)];
        b2s_t[t] = bs2[128 + t * 16 + (lane & 15)];
    }

    int bid = blockIdx.x;
    int cpx = (int)(gridDim.x >> 3);
    int swz = (bid & 7) * cpx + (bid >> 3);

    long nG = ((long)E + GEPW - 1) / GEPW;
    for (long g = (long)swz * 4 + wave; g < nG; g += (long)gridDim.x * 4) {
        long e0b = g * GEPW;
        int i0a[GEPW], i1a[GEPW];
        #pragma unroll
        for (int e = 0; e < GEPW; ++e) {
            long eid = e0b + e; if (eid >= E) eid = E - 1;
            int2 p = eperm[eid];
            i0a[e] = RFL(p.x); i1a[e] = RFL(p.y);
        }
        int vi_all = 0, vi1_all = 0;
        #pragma unroll
        for (int e = 0; e < GEPW; ++e) {
            vi_all  = (lane == e) ? i0a[e] : vi_all;
            vi1_all = (lane == e) ? i1a[e] : vi1_all;
        }
        // phase 1: AB gloads (oldest 16)
        #pragma unroll
        for (int e = 0; e < GEPW; ++e) {
            const char* srcAB = (lane < 32)
                ? ((const char*)Abf + (size_t)i0a[e] * 128 + lane * 4)
                : ((const char*)Bbf + (size_t)i1a[e] * 128 + (lane - 32) * 4);
            gload_lds4(srcAB, &stAB[wave][e][0]);
        }
        __builtin_amdgcn_sched_barrier(0);
        // phase 2: nv2 (8) + rel (1) + nv01 VGPR loads (16)
        #pragma unroll
        for (int p2 = 0; p2 < GEPW / 2; ++p2) {
            const char* src2 = (lane < 32)
                ? ((const char*)nv2bf + (size_t)i1a[2 * p2] * 128 + lane * 4)
                : ((const char*)nv2bf + (size_t)i1a[2 * p2 + 1] * 128 + (lane - 32) * 4);
            gload_lds4(src2, &stNV2[wave][p2][0]);
        }
        gload_lds4((const char*)relg + e0b * 12 + lane * 4, &relL[wave][0]);
        int eL0 = (lane >> 4) * 4;
        unsigned nv01r[4][4];
        #pragma unroll
        for (int rg = 0; rg < 4; ++rg) {
            int i1s = __builtin_amdgcn_ds_bpermute((eL0 + rg) * 4, vi1_all);
            const char* basep = (const char*)nv01p + (size_t)(unsigned)i1s * 256 + (lane & 15) * 4;
            nv01r[rg][0] = *(const unsigned*)(basep);
            nv01r[rg][1] = *(const unsigned*)(basep + 64);
            nv01r[rg][2] = *(const unsigned*)(basep + 128);
            nv01r[rg][3] = *(const unsigned*)(basep + 192);
        }
        __builtin_amdgcn_sched_barrier(0);
        asm volatile("s_waitcnt vmcnt(25)" ::: "memory");
        __builtin_amdgcn_sched_barrier(0);
        // h phase
        #pragma unroll
        for (int e = 0; e < GEPW; ++e) {
            float a = bf16_to_f32(stAB[wave][e][lane]);
            float b = bf16_to_f32(stAB[wave][e][64 + lane]);
            float h = silu_f(a + b + b1);
            *(float*)((char*)&stAB[wave][e][0] + ((lane * 4) ^ ((e & 7) << 5))) = h;
        }
        __builtin_amdgcn_sched_barrier(0);
        // MFMA
        f32x4 acc[12];
        f32x4 zz = {0.f, 0.f, 0.f, 0.f};
        #pragma unroll
        for (int t = 0; t < 12; ++t) acc[t] = zz;
        int row = lane & 15;
        #pragma unroll
        for (int kk = 0; kk < 2; ++kk) {
            int coff = (kk * 128 + ((lane >> 4) * 32)) ^ ((row & 7) << 5);
            const char* hp = (const char*)&stAB[wave][row][0] + coff;
            float4 lo = *(const float4*)hp;
            float4 hi = *(const float4*)(hp + 16);
            unsigned a0, a1, a2, a3;
            asm("v_cvt_pk_bf16_f32 %0, %1, %2" : "=v"(a0) : "v"(lo.x), "v"(lo.y));
            asm("v_cvt_pk_bf16_f32 %0, %1, %2" : "=v"(a1) : "v"(lo.z), "v"(lo.w));
            asm("v_cvt_pk_bf16_f32 %0, %1, %2" : "=v"(a2) : "v"(hi.x), "v"(hi.y));
            asm("v_cvt_pk_bf16_f32 %0, %1, %2" : "=v"(a3) : "v"(hi.z), "v"(hi.w));
            union { unsigned u[4]; bf16x8 v; } af;
            af.u[0] = a0; af.u[1] = a1; af.u[2] = a2; af.u[3] = a3;
            #pragma unroll
            for (int t = 0; t < 12; ++t) {
                bf16x8 bf = *(const bf16x8*)&w2frag[((t * 2 + kk) * 64 + lane) * 4];
                acc[t] = __builtin_amdgcn_mfma_f32_16x16x32_bf16(af.v, bf, acc[t], 0, 0, 0);
            }
        }
        asm volatile("s_waitcnt vmcnt(0)" ::: "memory");
        __builtin_amdgcn_sched_barrier(0);
        // scatter with in-register merge
        float aS[4]  = {0.f, 0.f, 0.f, 0.f};
        float aV0[4] = {0.f, 0.f, 0.f, 0.f};
        float aV1[4] = {0.f, 0.f, 0.f, 0.f};
        float aV2[4] = {0.f, 0.f, 0.f, 0.f};
        int icur = __builtin_amdgcn_ds_bpermute(eL0 * 4, vi_all);
        #pragma unroll
        for (int rg = 0; rg < 4; ++rg) {
            int e = eL0 + rg;
            int i0 = __builtin_amdgcn_ds_bpermute(e * 4, vi_all);
            bool ok = (e0b + e) < E;
            if (i0 != icur) {
                #pragma unroll
                for (int t = 0; t < 4; ++t) {
                    int dim = t * 16 + (lane & 15);
                    unsafeAtomicAdd(&out0[(size_t)(unsigned)icur * 64u + dim], aS[t]);
                    unsafeAtomicAdd(&out2[((size_t)(unsigned)icur * 3u + 0) * 64u + dim], aV0[t]);
                    unsafeAtomicAdd(&out2[((size_t)(unsigned)icur * 3u + 1) * 64u + dim], aV1[t]);
                    unsafeAtomicAdd(&out2[((size_t)(unsigned)icur * 3u + 2) * 64u + dim], aV2[t]);
                    aS[t] = 0.f; aV0[t] = 0.f; aV1[t] = 0.f; aV2[t] = 0.f;
                }
                icur = i0;
            }
            if (ok) {
                float r0v = relL[wave][e * 3 + 0];
                float r1v = relL[wave][e * 3 + 1];
                float r2v = relL[wave][e * 3 + 2];
                #pragma unroll
                for (int t = 0; t < 4; ++t) {
                    int dim = t * 16 + (lane & 15);
                    float gv = acc[t][rg]     + b2v_t[t];
                    float ge = acc[4 + t][rg] + b2e_t[t];
                    float ss = acc[8 + t][rg] + b2s_t[t];
                    float2 vv = bf2_lo_hi(nv01r[rg][t]);
                    float v2 = bf16_to_f32(stNV2[wave][e >> 1][(e & 1) * 64 + dim]);
                    aS[t]  += ss;
                    aV0[t] += gv * vv.x + ge * r0v;
                    aV1[t] += gv * vv.y + ge * r1v;
                    aV2[t] += gv * v2   + ge * r2v;
                }
            }
        }
        #pragma unroll
        for (int t = 0; t < 4; ++t) {
            int dim = t * 16 + (lane & 15);
            unsafeAtomicAdd(&out0[(size_t)(unsigned)icur * 64u + dim], aS[t]);
            unsafeAtomicAdd(&out2[((size_t)(unsigned)icur * 3u + 0) * 64u + dim], aV0[t]);
            unsafeAtomicAdd(&out2[((size_t)(unsigned)icur * 3u + 1) * 64u + dim], aV1[t]);
            unsafeAtomicAdd(&out2[((size_t)(unsigned)icur * 3u + 2) * 64u + dim], aV2[t]);
        }
    }
}

// ---------------- Kernel 3: triplets — bf16 lane-split staging, TPW=16
__global__ __launch_bounds__(256) void triplet_kernel(
    const ushort_t* __restrict__ Cbf, const ushort_t* __restrict__ Dmbf,
    const float* __restrict__ pos, const int* __restrict__ tidx,
    const float* __restrict__ bc1, const float* __restrict__ Wc2, const float* __restrict__ bc2,
    float* __restrict__ out1, int T)
{
    __shared__ __align__(16) float wT[64 * 64];            // 16 KiB
    __shared__ __align__(16) ushort_t stCD[4][TPW][128];   // 16 KiB: C|D1 -> h (f32)
    __shared__ __align__(16) ushort_t stDD[4][TPW][128];   // 16 KiB: D2|D3
    int tid = threadIdx.x;
    for (int i = tid; i < 64 * 64 / 4; i += 256)
        ((float4*)wT)[i] = ((const float4*)Wc2)[i];
    __syncthreads();
    int wave = RFL(tid >> 6);
    int lane = tid & 63;
    float b1 = bc1[lane];
    float b2 = bc2[lane] * 3.0f;
    for (long bb = (long)blockIdx.x * (4 * TPW); bb < T; bb += (long)gridDim.x * (4 * TPW)) {
        long t0 = bb + wave * TPW;
        int ib[TPW], it1[TPW], it2[TPW], it3[TPW];
        #pragma unroll
        for (int e = 0; e < TPW; ++e) {
            long t = t0 + e;
            int b = 0, t1 = 0, t2 = 0, t3 = 0;
            if (t < T) { int4 q = ((const int4*)tidx)[t]; b = q.x; t1 = q.y; t2 = q.z; t3 = q.w; }
            ib[e]  = RFL(b);
            it1[e] = RFL(t1);
            it2[e] = RFL(t2);
            it3[e] = RFL(t3);
        }
        // 2 lane-split gloads per triplet: (C|D1), (D2|D3) — 32 instrs, 8 KB in flight
        #pragma unroll
        for (int e = 0; e < TPW; ++e) {
            const char* srcA = (lane < 32)
                ? ((const char*)Cbf  + (size_t)ib[e]  * 128 + lane * 4)
                : ((const char*)Dmbf + (size_t)it1[e] * 128 + (lane - 32) * 4);
            gload_lds4(srcA, &stCD[wave][e][0]);
            const char* srcB = (lane < 32)
                ? ((const char*)Dmbf + (size_t)it2[e] * 128 + lane * 4)
                : ((const char*)Dmbf + (size_t)it3[e] * 128 + (lane - 32) * 4);
            gload_lds4(srcB, &stDD[wave][e][0]);
        }
        asm volatile("s_waitcnt vmcnt(0)" ::: "memory");
        float inv[TPW];
        #pragma unroll
        for (int e = 0; e < TPW; ++e) {
            float c  = bf16_to_f32(stCD[wave][e][lane]);
            float d1 = bf16_to_f32(stCD[wave][e][64 + lane]);
            float d2 = bf16_to_f32(stDD[wave][e][lane]);
            float d3 = bf16_to_f32(stDD[wave][e][64 + lane]);
            float hb = c + b1;
            float h = silu_f(hb + d1) + silu_f(hb + d2) + silu_f(hb + d3);
            ((float*)&stCD[wave][e][0])[lane] = h;
            int b = ib[e], t1 = it1[e], t2 = it2[e], t3 = it3[e];
            double pbx = pos[(size_t)b * 3], pby = pos[(size_t)b * 3 + 1], pbz = pos[(size_t)b * 3 + 2];
            double r1x = pbx - pos[(size_t)t1 * 3], r1y = pby - pos[(size_t)t1 * 3 + 1], r1z = pbz - pos[(size_t)t1 * 3 + 2];
            double r2x = pbx - pos[(size_t)t2 * 3], r2y = pby - pos[(size_t)t2 * 3 + 1], r2z = pbz - pos[(size_t)t2 * 3 + 2];
            double r3x = pbx - pos[(size_t)t3 * 3], r3y = pby - pos[(size_t)t3 * 3 + 1], r3z = pbz - pos[(size_t)t3 * 3 + 2];
            double cx = r2y * r3z - r2z * r3y;
            double cy = r2z * r3x - r2x * r3z;
            double cz = r2x * r3y - r2y * r3x;
            double stp = r1x * cx + r1y * cy + r1z * cz;
            inv[e] = (float)(1.0 / (stp + 0.01));
        }
        // matvec: per-e float4 broadcast reads (low register pressure at TPW=16)
        float acc[TPW];
        #pragma unroll
        for (int e = 0; e < TPW; ++e) acc[e] = 0.f;
        for (int k4 = 0; k4 < 64; k4 += 4) {
            float w0 = wT[(k4 + 0) * 64 + lane];
            float w1 = wT[(k4 + 1) * 64 + lane];
            float w2 = wT[(k4 + 2) * 64 + lane];
            float w3 = wT[(k4 + 3) * 64 + lane];
            #pragma unroll
            for (int e = 0; e < TPW; ++e) {
                float4 hk = *(const float4*)&((const float*)&stCD[wave][e][0])[k4];
                acc[e] += hk.x * w0 + hk.y * w1 + hk.z * w2 + hk.w * w3;
            }
        }
        #pragma unroll
        for (int e = 0; e < TPW; ++e) {
            long t = t0 + e;
            if (t >= T) break;
            unsafeAtomicAdd(&out1[(size_t)ib[e] * DD + lane], (acc[e] + b2) * inv[e]);
        }
    }
}

extern "C" void kernel_launch(void* const* d_in, const int* in_sizes, int n_in,
                              void* d_out, int out_size, void* d_ws, size_t ws_size,
                              hipStream_t stream)
{
    const float* ns  = (const float*)d_in[0];
    const float* nc  = (const float*)d_in[1];
    const float* nv  = (const float*)d_in[2];
    const float* pos = (const float*)d_in[3];
    const int* eidx  = (const int*)d_in[4];
    const int* tidx  = (const int*)d_in[5];
    const float* Ws1 = (const float*)d_in[6];
    const float* bs1 = (const float*)d_in[7];
    const float* Ws2 = (const float*)d_in[8];
    const float* bs2 = (const float*)d_in[9];
    const float* Wc1 = (const float*)d_in[10];
    const float* bc1 = (const float*)d_in[11];
    const float* Wc2 = (const float*)d_in[12];
    const float* bc2 = (const float*)d_in[13];
    const float* WV  = (const float*)d_in[14];
    const float* bV  = (const float*)d_in[15];

    int N = in_sizes[0] / 64;
    int E = in_sizes[4] / 2;
    int T = in_sizes[5] / 4;

    float* out0 = (float*)d_out;
    float* out1 = out0 + (size_t)N * 64;
    float* out2 = out1 + (size_t)N * 64;

    float* relg = (float*)d_ws;                        // E*3 + 64 floats
    int2* eperm = (int2*)(relg + (size_t)E * 3 + 64);  // E int2
    int* counts = (int*)(eperm + (size_t)E);
    int* cursor = counts + N;
    unsigned* nv01p = (unsigned*)(cursor + N);         // N*64 uint
    ushort_t* Abf   = (ushort_t*)(nv01p + (size_t)N * 64);
    ushort_t* Bbf   = Abf + (size_t)N * 64;
    ushort_t* nv2bf = Bbf + (size_t)N * 64;
    ushort_t* Cbf   = nv2bf + (size_t)N * 64;
    ushort_t* Dmbf  = Cbf + (size_t)N * 64;

    int sblocks = (E + 255) / 256;

    hipMemsetAsync(counts, 0, (size_t)N * sizeof(int), stream);
    hist_kernel<<<sblocks, 256, 0, stream>>>(eidx, counts, E);
    scan_kernel<<<1, 1024, 0, stream>>>(counts, cursor, N);
    fused_prep_kernel<<<sblocks + 4096, 256, 0, stream>>>(
        eidx, pos, cursor, eperm, relg,
        ns, nc, Ws1, Wc1, Abf, Bbf, Cbf, Dmbf, out1,
        nv, WV, bV, out0, out2, nv01p, nv2bf,
        N, E, sblocks);
    edge_kernel<<<4096, 256, 0, stream>>>(Abf, Bbf, nv01p, nv2bf, relg, eperm,
                                          bs1, Ws2, bs2, out0, out2, E);
    triplet_kernel<<<2048, 256, 0, stream>>>(Cbf, Dmbf, pos, tidx, bc1, Wc2, bc2, out1, T);
}

// Round 17
// 925.692 us; speedup vs baseline: 1.1953x; 1.1953x over previous
//
#include <hip/hip_runtime.h>
#include <math.h>

#define DD 64
typedef unsigned short ushort_t;
typedef __attribute__((ext_vector_type(8))) short bf16x8;
typedef __attribute__((ext_vector_type(4))) float f32x4;

#define GEPW 16
#define TPW 4

__device__ __forceinline__ float silu_f(float x) {
    return x / (1.0f + __expf(-x));
}

__device__ __forceinline__ unsigned f32_to_bf16_rne(float x) {
    unsigned u = __float_as_uint(x);
    unsigned r = ((u >> 16) & 1u) + 0x7fffu;
    return (u + r) >> 16;
}

__device__ __forceinline__ float bf16_to_f32(ushort_t v) {
    return __uint_as_float(((unsigned)v) << 16);
}

__device__ __forceinline__ void gload_lds4(const void* gsrc, void* lds_base) {
    __builtin_amdgcn_global_load_lds(
        (const __attribute__((address_space(1))) void*)gsrc,
        (__attribute__((address_space(3))) void*)lds_base,
        4, 0, 0);
}

#define RFL(x) __builtin_amdgcn_readfirstlane(x)

// ---------------- fused prep: rel | node_transform | node_vector
__global__ __launch_bounds__(256) void fused_prep_kernel(
    const int* __restrict__ eidx, const float* __restrict__ pos, float* __restrict__ relg,
    const float* __restrict__ ns, const float* __restrict__ nc,
    const float* __restrict__ Ws1, const float* __restrict__ Wc1,
    ushort_t* __restrict__ Abf, ushort_t* __restrict__ Bbf,
    float* __restrict__ C, float* __restrict__ Dm, float* __restrict__ out1,
    const float* __restrict__ nv, const float* __restrict__ WV, const float* __restrict__ bV,
    float* __restrict__ out0, float* __restrict__ out2, ushort_t* __restrict__ nvbf,
    int N, int E, int relB)
{
    __shared__ __align__(16) char smem[69632];
    int tid = threadIdx.x;
    int bx = blockIdx.x;

    if (bx < relB) {
        // -------- rel: rel[e] = pos[e1] - pos[e0] --------
        int e = bx * 256 + tid;
        if (e < E) {
            int2 p = ((const int2*)eidx)[e];
            relg[3 * (size_t)e + 0] = pos[(size_t)p.y * 3 + 0] - pos[(size_t)p.x * 3 + 0];
            relg[3 * (size_t)e + 1] = pos[(size_t)p.y * 3 + 1] - pos[(size_t)p.x * 3 + 1];
            relg[3 * (size_t)e + 2] = pos[(size_t)p.y * 3 + 2] - pos[(size_t)p.x * 3 + 2];
        }
        return;
    }
    if (bx < relB + 2048) {
        // -------- node_transform: A,B (bf16), C,D (f32), out1 --------
        int blk = bx - relB;
        float* w1   = (float*)smem;                  // 32 KiB
        float* wc1s = (float*)(smem + 32768);        // 32 KiB
        float* xs   = (float*)(smem + 65536);        // 2 KiB
        float* ys   = (float*)(smem + 67584);        // 2 KiB
        for (int i = tid; i < 128 * 64 / 4; i += 256) {
            ((float4*)w1)[i]   = ((const float4*)Ws1)[i];
            ((float4*)wc1s)[i] = ((const float4*)Wc1)[i];
        }
        __syncthreads();
        int wave = tid >> 6, lane = tid & 63;
        for (int nb = blk * 8; nb < N; nb += 2048 * 8) {
            int n0 = nb + wave * 2;
            #pragma unroll
            for (int s = 0; s < 2; ++s) {
                int n = n0 + s;
                float xv = 0.f, yv = 0.f;
                if (n < N) { xv = ns[(size_t)n * DD + lane]; yv = nc[(size_t)n * DD + lane]; }
                xs[(wave * 2 + s) * 64 + lane] = xv;
                ys[(wave * 2 + s) * 64 + lane] = yv;
            }
            float aA[2] = {0.f, 0.f}, aB[2] = {0.f, 0.f}, aC[2] = {0.f, 0.f}, aD[2] = {0.f, 0.f};
            for (int k = 0; k < 64; ++k) {
                float wa  = w1[k * 64 + lane];
                float wb  = w1[(64 + k) * 64 + lane];
                float wca = wc1s[k * 64 + lane];
                float wcb = wc1s[(64 + k) * 64 + lane];
                #pragma unroll
                for (int s = 0; s < 2; ++s) {
                    float xk = xs[(wave * 2 + s) * 64 + k];
                    float yk = ys[(wave * 2 + s) * 64 + k];
                    aA[s] += xk * wa;  aB[s] += xk * wb;
                    aC[s] += yk * wca; aD[s] += yk * wcb;
                }
            }
            #pragma unroll
            for (int s = 0; s < 2; ++s) {
                int n = n0 + s;
                if (n < N) {
                    Abf[(size_t)n * DD + lane] = (ushort_t)f32_to_bf16_rne(aA[s]);
                    Bbf[(size_t)n * DD + lane] = (ushort_t)f32_to_bf16_rne(aB[s]);
                    C[(size_t)n * DD + lane]  = aC[s];
                    Dm[(size_t)n * DD + lane] = aD[s];
                    out1[(size_t)n * DD + lane] = ys[(wave * 2 + s) * 64 + lane];
                }
            }
            __syncthreads();
        }
        return;
    }
    // -------- node_vector: out0, out2 (f32), nvbf ([n][3][64] bf16) --------
    {
        int blk = bx - relB - 2048;
        float* wv = (float*)smem;                    // 16 KiB
        float* vs = (float*)(smem + 16384);          // 6 KiB
        for (int i = tid; i < 64 * 64 / 4; i += 256)
            ((float4*)wv)[i] = ((const float4*)WV)[i];
        __syncthreads();
        int wave = tid >> 6, lane = tid & 63;
        float bVj = bV[lane];
        for (int nb = blk * 8; nb < N; nb += 2048 * 8) {
            int n0 = nb + wave * 2;
            #pragma unroll
            for (int s = 0; s < 2; ++s) {
                int n = n0 + s;
                float v0 = 0.f, v1 = 0.f, v2 = 0.f;
                if (n < N) {
                    v0 = nv[((size_t)n * 3 + 0) * DD + lane];
                    v1 = nv[((size_t)n * 3 + 1) * DD + lane];
                    v2 = nv[((size_t)n * 3 + 2) * DD + lane];
                }
                vs[((wave * 2 + s) * 3 + 0) * 64 + lane] = v0;
                vs[((wave * 2 + s) * 3 + 1) * 64 + lane] = v1;
                vs[((wave * 2 + s) * 3 + 2) * 64 + lane] = v2;
            }
            float a0[2], a1[2], a2[2];
            #pragma unroll
            for (int s = 0; s < 2; ++s) { a0[s] = bVj; a1[s] = bVj; a2[s] = bVj; }
            for (int k = 0; k < 64; ++k) {
                float w = wv[k * 64 + lane];
                #pragma unroll
                for (int s = 0; s < 2; ++s) {
                    a0[s] += vs[((wave * 2 + s) * 3 + 0) * 64 + k] * w;
                    a1[s] += vs[((wave * 2 + s) * 3 + 1) * 64 + k] * w;
                    a2[s] += vs[((wave * 2 + s) * 3 + 2) * 64 + k] * w;
                }
            }
            #pragma unroll
            for (int s = 0; s < 2; ++s) {
                int n = n0 + s;
                if (n < N) {
                    float norm = sqrtf(a0[s] * a0[s] + a1[s] * a1[s] + a2[s] * a2[s]);
                    float x = ns[(size_t)n * DD + lane];
                    out0[(size_t)n * DD + lane] = x * (1.f + norm);
                    float v0 = vs[((wave * 2 + s) * 3 + 0) * 64 + lane];
                    float v1 = vs[((wave * 2 + s) * 3 + 1) * 64 + lane];
                    float v2 = vs[((wave * 2 + s) * 3 + 2) * 64 + lane];
                    out2[((size_t)n * 3 + 0) * DD + lane] = v0;
                    out2[((size_t)n * 3 + 1) * DD + lane] = v1;
                    out2[((size_t)n * 3 + 2) * DD + lane] = v2;
                    nvbf[((size_t)n * 3 + 0) * DD + lane] = (ushort_t)f32_to_bf16_rne(v0);
                    nvbf[((size_t)n * 3 + 1) * DD + lane] = (ushort_t)f32_to_bf16_rne(v1);
                    nvbf[((size_t)n * 3 + 2) * DD + lane] = (ushort_t)f32_to_bf16_rne(v2);
                }
            }
            __syncthreads();
        }
    }
}

// ---------------- Kernel 2: edges — round-11 body + AB-first split-wait
__global__ __launch_bounds__(256) void edge_kernel(
    const ushort_t* __restrict__ Abf, const ushort_t* __restrict__ Bbf,
    const ushort_t* __restrict__ nvbf, const float* __restrict__ relg,
    const int* __restrict__ eidx,
    const float* __restrict__ bs1, const float* __restrict__ Ws2, const float* __restrict__ bs2,
    float* __restrict__ out0, float* __restrict__ out2, int E)
{
    __shared__ __align__(16) unsigned w2frag[12 * 2 * 64 * 4];   // 24 KiB
    __shared__ __align__(16) ushort_t stAB[4][GEPW][128];        // 16 KiB
    __shared__ __align__(16) ushort_t stNV01[4][GEPW][132];      // 16.5 KiB
    __shared__ __align__(16) ushort_t stNV2[4][GEPW / 2][132];   // 8.25 KiB
    __shared__ __align__(16) float    relL[4][64];               // 1 KiB
    int tid = threadIdx.x;
    for (int i = tid; i < 12 * 2 * 64; i += 256) {
        int t  = i >> 7;
        int kk = (i >> 6) & 1;
        int l  = i & 63;
        int k0 = kk * 32 + (l >> 4) * 8;
        int col = t * 16 + (l & 15);
        #pragma unroll
        for (int jp = 0; jp < 4; ++jp) {
            float a = Ws2[(size_t)(k0 + 2 * jp) * 192 + col];
            float b = Ws2[(size_t)(k0 + 2 * jp + 1) * 192 + col];
            w2frag[i * 4 + jp] = f32_to_bf16_rne(a) | (f32_to_bf16_rne(b) << 16);
        }
    }
    __syncthreads();
    int wave = RFL(tid >> 6);
    int lane = tid & 63;
    float b1 = bs1[lane];
    float b2v_t[4], b2e_t[4], b2s_t[4];
    #pragma unroll
    for (int t = 0; t < 4; ++t) {
        b2v_t[t] = bs2[t * 16 + (lane & 15)];
        b2e_t[t] = bs2[64 + t * 16 + (lane & 15)];
        b2s_t[t] = bs2[128 + t * 16 + (lane & 15)];
    }

    long nG = ((long)E + GEPW - 1) / GEPW;
    for (long g = (long)blockIdx.x * 4 + wave; g < nG; g += (long)gridDim.x * 4) {
        long e0b = g * GEPW;
        int i0a[GEPW], i1a[GEPW];
        #pragma unroll
        for (int e = 0; e < GEPW; ++e) {
            long eid = e0b + e; if (eid >= E) eid = E - 1;
            int2 p = ((const int2*)eidx)[eid];
            i0a[e] = RFL(p.x); i1a[e] = RFL(p.y);
        }
        // ---- phase 1: AB gloads (oldest 16 — h/MFMA inputs)
        #pragma unroll
        for (int e = 0; e < GEPW; ++e) {
            const char* srcAB = (lane < 32)
                ? ((const char*)Abf + (size_t)i0a[e] * 128 + lane * 4)
                : ((const char*)Bbf + (size_t)i1a[e] * 128 + (lane - 32) * 4);
            gload_lds4(srcAB, &stAB[wave][e][0]);
        }
        __builtin_amdgcn_sched_barrier(0);
        // ---- phase 2: nv01 (16) + nv2 (8) + rel (1) — scatter inputs
        #pragma unroll
        for (int e = 0; e < GEPW; ++e)
            gload_lds4((const char*)nvbf + (size_t)i1a[e] * 384 + lane * 4, &stNV01[wave][e][0]);
        #pragma unroll
        for (int p2 = 0; p2 < GEPW / 2; ++p2) {
            const char* src2 = (lane < 32)
                ? ((const char*)nvbf + (size_t)i1a[2 * p2] * 384 + 256 + lane * 4)
                : ((const char*)nvbf + (size_t)i1a[2 * p2 + 1] * 384 + 256 + (lane - 32) * 4);
            gload_lds4(src2, &stNV2[wave][p2][0]);
        }
        gload_lds4((const char*)relg + e0b * 12 + lane * 4, &relL[wave][0]);
        __builtin_amdgcn_sched_barrier(0);
        // wait for AB only (25 newer NV/rel ops still in flight)
        asm volatile("s_waitcnt vmcnt(25)" ::: "memory");
        __builtin_amdgcn_sched_barrier(0);
        // ---- h phase (XOR-swizzled f32 write over the A|B row)
        #pragma unroll
        for (int e = 0; e < GEPW; ++e) {
            float a = bf16_to_f32(stAB[wave][e][lane]);
            float b = bf16_to_f32(stAB[wave][e][64 + lane]);
            float h = silu_f(a + b + b1);
            *(float*)((char*)&stAB[wave][e][0] + ((lane * 4) ^ ((e & 7) << 5))) = h;
        }
        __builtin_amdgcn_sched_barrier(0);
        // ---- MFMA: G[16x192] = H[16x64] @ Ws2[64x192]  (overlaps NV latency)
        f32x4 acc[12];
        f32x4 zz = {0.f, 0.f, 0.f, 0.f};
        #pragma unroll
        for (int t = 0; t < 12; ++t) acc[t] = zz;
        int row = lane & 15;
        #pragma unroll
        for (int kk = 0; kk < 2; ++kk) {
            int coff = (kk * 128 + ((lane >> 4) * 32)) ^ ((row & 7) << 5);
            const char* hp = (const char*)&stAB[wave][row][0] + coff;
            float4 lo = *(const float4*)hp;
            float4 hi = *(const float4*)(hp + 16);
            unsigned a0, a1, a2, a3;
            asm("v_cvt_pk_bf16_f32 %0, %1, %2" : "=v"(a0) : "v"(lo.x), "v"(lo.y));
            asm("v_cvt_pk_bf16_f32 %0, %1, %2" : "=v"(a1) : "v"(lo.z), "v"(lo.w));
            asm("v_cvt_pk_bf16_f32 %0, %1, %2" : "=v"(a2) : "v"(hi.x), "v"(hi.y));
            asm("v_cvt_pk_bf16_f32 %0, %1, %2" : "=v"(a3) : "v"(hi.z), "v"(hi.w));
            union { unsigned u[4]; bf16x8 v; } af;
            af.u[0] = a0; af.u[1] = a1; af.u[2] = a2; af.u[3] = a3;
            #pragma unroll
            for (int t = 0; t < 12; ++t) {
                bf16x8 bf = *(const bf16x8*)&w2frag[((t * 2 + kk) * 64 + lane) * 4];
                acc[t] = __builtin_amdgcn_mfma_f32_16x16x32_bf16(af.v, bf, acc[t], 0, 0, 0);
            }
        }
        // drain NV/rel before scatter reads them
        asm volatile("s_waitcnt vmcnt(0)" ::: "memory");
        __builtin_amdgcn_sched_barrier(0);
        // ---- scatter straight from fragments (round-11 direct form)
        int vi_all = 0;
        #pragma unroll
        for (int e = 0; e < GEPW; ++e) vi_all = (lane == e) ? i0a[e] : vi_all;
        int eLane0 = (lane >> 4) * 4;
        #pragma unroll
        for (int rg = 0; rg < 4; ++rg) {
            int e = eLane0 + rg;
            int i0 = __builtin_amdgcn_ds_bpermute(e * 4, vi_all);
            bool ok = (e0b + e) < E;
            float r0v = relL[wave][e * 3 + 0];
            float r1v = relL[wave][e * 3 + 1];
            float r2v = relL[wave][e * 3 + 2];
            #pragma unroll
            for (int t = 0; t < 4; ++t) {
                int dim = t * 16 + (lane & 15);
                float gv = acc[t][rg]     + b2v_t[t];
                float ge = acc[4 + t][rg] + b2e_t[t];
                float ss = acc[8 + t][rg] + b2s_t[t];
                float v0 = bf16_to_f32(stNV01[wave][e][dim]);
                float v1 = bf16_to_f32(stNV01[wave][e][64 + dim]);
                float v2 = bf16_to_f32(stNV2[wave][e >> 1][(e & 1) * 64 + dim]);
                if (ok) {
                    unsafeAtomicAdd(&out0[(size_t)(unsigned)i0 * 64u + dim], ss);
                    unsafeAtomicAdd(&out2[((size_t)(unsigned)i0 * 3u + 0) * 64u + dim], gv * v0 + ge * r0v);
                    unsafeAtomicAdd(&out2[((size_t)(unsigned)i0 * 3u + 1) * 64u + dim], gv * v1 + ge * r1v);
                    unsafeAtomicAdd(&out2[((size_t)(unsigned)i0 * 3u + 2) * 64u + dim], gv * v2 + ge * r2v);
                }
            }
        }
    }
}

// ---------------- Kernel 3: triplets — round-11 version (TPW=4, f32)
__global__ __launch_bounds__(256) void triplet_kernel(
    const float* __restrict__ C, const float* __restrict__ Dm,
    const float* __restrict__ pos, const int* __restrict__ tidx,
    const float* __restrict__ bc1, const float* __restrict__ Wc2, const float* __restrict__ bc2,
    float* __restrict__ out1, int T)
{
    __shared__ float wT[64 * 64];
    __shared__ float stC[4][TPW][64];
    __shared__ float stD[4][TPW][3][64];
    int tid = threadIdx.x;
    for (int i = tid; i < 64 * 64 / 4; i += 256)
        ((float4*)wT)[i] = ((const float4*)Wc2)[i];
    __syncthreads();
    int wave = RFL(tid >> 6);
    int lane = tid & 63;
    float b1 = bc1[lane];
    float b2 = bc2[lane] * 3.0f;
    for (long bb = (long)blockIdx.x * (4 * TPW); bb < T; bb += (long)gridDim.x * (4 * TPW)) {
        long t0 = bb + wave * TPW;
        int ib[TPW], it1[TPW], it2[TPW], it3[TPW];
        #pragma unroll
        for (int e = 0; e < TPW; ++e) {
            long t = t0 + e;
            int b = 0, t1 = 0, t2 = 0, t3 = 0;
            if (t < T) { int4 q = ((const int4*)tidx)[t]; b = q.x; t1 = q.y; t2 = q.z; t3 = q.w; }
            ib[e]  = RFL(b);
            it1[e] = RFL(t1);
            it2[e] = RFL(t2);
            it3[e] = RFL(t3);
        }
        #pragma unroll
        for (int e = 0; e < TPW; ++e) {
            gload_lds4(C  + (size_t)ib[e]  * DD + lane, &stC[wave][e][0]);
            gload_lds4(Dm + (size_t)it1[e] * DD + lane, &stD[wave][e][0][0]);
            gload_lds4(Dm + (size_t)it2[e] * DD + lane, &stD[wave][e][1][0]);
            gload_lds4(Dm + (size_t)it3[e] * DD + lane, &stD[wave][e][2][0]);
        }
        asm volatile("s_waitcnt vmcnt(0)" ::: "memory");
        float inv[TPW];
        #pragma unroll
        for (int e = 0; e < TPW; ++e) {
            float hb = stC[wave][e][lane] + b1;
            float h = silu_f(hb + stD[wave][e][0][lane])
                    + silu_f(hb + stD[wave][e][1][lane])
                    + silu_f(hb + stD[wave][e][2][lane]);
            stC[wave][e][lane] = h;
            int b = ib[e], t1 = it1[e], t2 = it2[e], t3 = it3[e];
            double pbx = pos[(size_t)b * 3], pby = pos[(size_t)b * 3 + 1], pbz = pos[(size_t)b * 3 + 2];
            double r1x = pbx - pos[(size_t)t1 * 3], r1y = pby - pos[(size_t)t1 * 3 + 1], r1z = pbz - pos[(size_t)t1 * 3 + 2];
            double r2x = pbx - pos[(size_t)t2 * 3], r2y = pby - pos[(size_t)t2 * 3 + 1], r2z = pbz - pos[(size_t)t2 * 3 + 2];
            double r3x = pbx - pos[(size_t)t3 * 3], r3y = pby - pos[(size_t)t3 * 3 + 1], r3z = pbz - pos[(size_t)t3 * 3 + 2];
            double cx = r2y * r3z - r2z * r3y;
            double cy = r2z * r3x - r2x * r3z;
            double cz = r2x * r3y - r2y * r3x;
            double stp = r1x * cx + r1y * cy + r1z * cz;
            inv[e] = (float)(1.0 / (stp + 0.01));
        }
        float acc[TPW];
        #pragma unroll
        for (int e = 0; e < TPW; ++e) acc[e] = 0.f;
        for (int k4 = 0; k4 < 64; k4 += 4) {
            float4 hk[TPW];
            #pragma unroll
            for (int e = 0; e < TPW; ++e) hk[e] = *(const float4*)&stC[wave][e][k4];
            #pragma unroll
            for (int kk = 0; kk < 4; ++kk) {
                float wk = wT[(k4 + kk) * 64 + lane];
                #pragma unroll
                for (int e = 0; e < TPW; ++e) acc[e] += (&hk[e].x)[kk] * wk;
            }
        }
        #pragma unroll
        for (int e = 0; e < TPW; ++e) {
            long t = t0 + e;
            if (t >= T) break;
            unsafeAtomicAdd(&out1[(size_t)ib[e] * DD + lane], (acc[e] + b2) * inv[e]);
        }
    }
}

extern "C" void kernel_launch(void* const* d_in, const int* in_sizes, int n_in,
                              void* d_out, int out_size, void* d_ws, size_t ws_size,
                              hipStream_t stream)
{
    const float* ns  = (const float*)d_in[0];
    const float* nc  = (const float*)d_in[1];
    const float* nv  = (const float*)d_in[2];
    const float* pos = (const float*)d_in[3];
    const int* eidx  = (const int*)d_in[4];
    const int* tidx  = (const int*)d_in[5];
    const float* Ws1 = (const float*)d_in[6];
    const float* bs1 = (const float*)d_in[7];
    const float* Ws2 = (const float*)d_in[8];
    const float* bs2 = (const float*)d_in[9];
    const float* Wc1 = (const float*)d_in[10];
    const float* bc1 = (const float*)d_in[11];
    const float* Wc2 = (const float*)d_in[12];
    const float* bc2 = (const float*)d_in[13];
    const float* WV  = (const float*)d_in[14];
    const float* bV  = (const float*)d_in[15];

    int N = in_sizes[0] / 64;
    int E = in_sizes[4] / 2;
    int T = in_sizes[5] / 4;

    float* out0 = (float*)d_out;
    float* out1 = out0 + (size_t)N * 64;
    float* out2 = out1 + (size_t)N * 64;

    // workspace: C, Dm, relg (f32), then bf16 arrays
    float* C    = (float*)d_ws;
    float* Dm   = C + (size_t)N * 64;
    float* relg = Dm + (size_t)N * 64;                 // E*3 + 64 floats
    ushort_t* Abf  = (ushort_t*)(relg + (size_t)E * 3 + 64);
    ushort_t* Bbf  = Abf + (size_t)N * 64;
    ushort_t* nvbf = Bbf + (size_t)N * 64;

    int relB = (E + 255) / 256;

    fused_prep_kernel<<<relB + 4096, 256, 0, stream>>>(
        eidx, pos, relg,
        ns, nc, Ws1, Wc1, Abf, Bbf, C, Dm, out1,
        nv, WV, bV, out0, out2, nvbf,
        N, E, relB);
    edge_kernel<<<4096, 256, 0, stream>>>(Abf, Bbf, nvbf, relg, eidx,
                                          bs1, Ws2, bs2, out0, out2, E);
    triplet_kernel<<<4096, 256, 0, stream>>>(C, Dm, pos, tidx, bc1, Wc2, bc2, out1, T);
}

// Round 18
// 915.764 us; speedup vs baseline: 1.2083x; 1.0108x over previous
//
#include <hip/hip_runtime.h>
#include <math.h>

#define DD 64
typedef unsigned short ushort_t;
typedef __attribute__((ext_vector_type(8))) short bf16x8;
typedef __attribute__((ext_vector_type(4))) float f32x4;

__device__ __forceinline__ float silu_f(float x) {
    return x / (1.0f + __expf(-x));
}

__device__ __forceinline__ unsigned f32_to_bf16_rne(float x) {
    unsigned u = __float_as_uint(x);
    unsigned r = ((u >> 16) & 1u) + 0x7fffu;
    return (u + r) >> 16;
}

__device__ __forceinline__ float bf16_to_f32(ushort_t v) {
    return __uint_as_float(((unsigned)v) << 16);
}

__device__ __forceinline__ void gload_lds4(const void* gsrc, void* lds_base) {
    __builtin_amdgcn_global_load_lds(
        (const __attribute__((address_space(1))) void*)gsrc,
        (__attribute__((address_space(3))) void*)lds_base,
        4, 0, 0);
}

#define RFL(x) __builtin_amdgcn_readfirstlane(x)

// ---------------- prep: rel[e] = pos[e1] - pos[e0]  ([E][3] f32, padded)
__global__ __launch_bounds__(256) void rel_kernel(const int* __restrict__ eidx,
                                                  const float* __restrict__ pos,
                                                  float* __restrict__ relg, int E)
{
    int e = blockIdx.x * 256 + threadIdx.x;
    if (e < E) {
        int2 p = ((const int2*)eidx)[e];
        relg[3 * (size_t)e + 0] = pos[(size_t)p.y * 3 + 0] - pos[(size_t)p.x * 3 + 0];
        relg[3 * (size_t)e + 1] = pos[(size_t)p.y * 3 + 1] - pos[(size_t)p.x * 3 + 1];
        relg[3 * (size_t)e + 2] = pos[(size_t)p.y * 3 + 2] - pos[(size_t)p.x * 3 + 2];
    }
}

// ---------------- Kernel 1a: per-node A,B (bf16), C,D (f32) + out1 init
__global__ __launch_bounds__(256) void node_transform_kernel(
    const float* __restrict__ ns, const float* __restrict__ nc,
    const float* __restrict__ Ws1, const float* __restrict__ Wc1,
    ushort_t* __restrict__ Abf, ushort_t* __restrict__ Bbf,
    float* __restrict__ C, float* __restrict__ Dm,
    float* __restrict__ out1, int N)
{
    __shared__ float w1[128 * 64];
    __shared__ float wc1s[128 * 64];
    __shared__ float xs[4][2][64];
    __shared__ float ys[4][2][64];
    int tid = threadIdx.x;
    for (int i = tid; i < 128 * 64 / 4; i += 256) {
        ((float4*)w1)[i]   = ((const float4*)Ws1)[i];
        ((float4*)wc1s)[i] = ((const float4*)Wc1)[i];
    }
    __syncthreads();
    int wave = tid >> 6, lane = tid & 63;
    for (int nb = blockIdx.x * 8; nb < N; nb += gridDim.x * 8) {
        int n0 = nb + wave * 2;
        #pragma unroll
        for (int s = 0; s < 2; ++s) {
            int n = n0 + s;
            float xv = 0.f, yv = 0.f;
            if (n < N) { xv = ns[(size_t)n * DD + lane]; yv = nc[(size_t)n * DD + lane]; }
            xs[wave][s][lane] = xv;
            ys[wave][s][lane] = yv;
        }
        float aA[2] = {0.f, 0.f}, aB[2] = {0.f, 0.f}, aC[2] = {0.f, 0.f}, aD[2] = {0.f, 0.f};
        for (int k = 0; k < 64; ++k) {
            float wa  = w1[k * 64 + lane];
            float wb  = w1[(64 + k) * 64 + lane];
            float wca = wc1s[k * 64 + lane];
            float wcb = wc1s[(64 + k) * 64 + lane];
            #pragma unroll
            for (int s = 0; s < 2; ++s) {
                float xk = xs[wave][s][k];
                float yk = ys[wave][s][k];
                aA[s] += xk * wa;  aB[s] += xk * wb;
                aC[s] += yk * wca; aD[s] += yk * wcb;
            }
        }
        #pragma unroll
        for (int s = 0; s < 2; ++s) {
            int n = n0 + s;
            if (n < N) {
                Abf[(size_t)n * DD + lane] = (ushort_t)f32_to_bf16_rne(aA[s]);
                Bbf[(size_t)n * DD + lane] = (ushort_t)f32_to_bf16_rne(aB[s]);
                C[(size_t)n * DD + lane]  = aC[s];
                Dm[(size_t)n * DD + lane] = aD[s];
                out1[(size_t)n * DD + lane] = ys[wave][s][lane];
            }
        }
    }
}

// ---------------- Kernel 1b: Vv norm -> out0 base, out2 base (nv f32) + nvbf (bf16)
__global__ __launch_bounds__(256) void node_vector_kernel(
    const float* __restrict__ ns, const float* __restrict__ nv,
    const float* __restrict__ WV, const float* __restrict__ bV,
    float* __restrict__ out0, float* __restrict__ out2,
    ushort_t* __restrict__ nvbf, int N)
{
    __shared__ float wv[64 * 64];
    __shared__ float vs[4][2][3][64];
    int tid = threadIdx.x;
    for (int i = tid; i < 64 * 64 / 4; i += 256)
        ((float4*)wv)[i] = ((const float4*)WV)[i];
    __syncthreads();
    int wave = tid >> 6, lane = tid & 63;
    float bVj = bV[lane];
    for (int nb = blockIdx.x * 8; nb < N; nb += gridDim.x * 8) {
        int n0 = nb + wave * 2;
        #pragma unroll
        for (int s = 0; s < 2; ++s) {
            int n = n0 + s;
            float v0 = 0.f, v1 = 0.f, v2 = 0.f;
            if (n < N) {
                v0 = nv[((size_t)n * 3 + 0) * DD + lane];
                v1 = nv[((size_t)n * 3 + 1) * DD + lane];
                v2 = nv[((size_t)n * 3 + 2) * DD + lane];
            }
            vs[wave][s][0][lane] = v0; vs[wave][s][1][lane] = v1; vs[wave][s][2][lane] = v2;
        }
        float a0[2], a1[2], a2[2];
        #pragma unroll
        for (int s = 0; s < 2; ++s) { a0[s] = bVj; a1[s] = bVj; a2[s] = bVj; }
        for (int k = 0; k < 64; ++k) {
            float w = wv[k * 64 + lane];
            #pragma unroll
            for (int s = 0; s < 2; ++s) {
                a0[s] += vs[wave][s][0][k] * w;
                a1[s] += vs[wave][s][1][k] * w;
                a2[s] += vs[wave][s][2][k] * w;
            }
        }
        #pragma unroll
        for (int s = 0; s < 2; ++s) {
            int n = n0 + s;
            if (n < N) {
                float norm = sqrtf(a0[s] * a0[s] + a1[s] * a1[s] + a2[s] * a2[s]);
                float x = ns[(size_t)n * DD + lane];
                out0[(size_t)n * DD + lane] = x * (1.f + norm);
                float v0 = vs[wave][s][0][lane], v1 = vs[wave][s][1][lane], v2 = vs[wave][s][2][lane];
                out2[((size_t)n * 3 + 0) * DD + lane] = v0;
                out2[((size_t)n * 3 + 1) * DD + lane] = v1;
                out2[((size_t)n * 3 + 2) * DD + lane] = v2;
                nvbf[((size_t)n * 3 + 0) * DD + lane] = (ushort_t)f32_to_bf16_rne(v0);
                nvbf[((size_t)n * 3 + 1) * DD + lane] = (ushort_t)f32_to_bf16_rne(v1);
                nvbf[((size_t)n * 3 + 2) * DD + lane] = (ushort_t)f32_to_bf16_rne(v2);
            }
        }
    }
}

// ---------------- Kernel 2: edges — 16 edges/wave, MFMA matvec
#define GEPW 16
__global__ __launch_bounds__(256) void edge_kernel(
    const ushort_t* __restrict__ Abf, const ushort_t* __restrict__ Bbf,
    const ushort_t* __restrict__ nvbf, const float* __restrict__ relg,
    const int* __restrict__ eidx,
    const float* __restrict__ bs1, const float* __restrict__ Ws2, const float* __restrict__ bs2,
    float* __restrict__ out0, float* __restrict__ out2, int E)
{
    // B-fragments of Ws2 in MFMA-ready order: [t][kk][lane][jp] packed bf16x2
    __shared__ unsigned w2frag[12 * 2 * 64 * 4];   // 24 KiB
    __shared__ ushort_t stAB[4][GEPW][128];        // 16 KiB: A|B rows -> h (f32, swizzled)
    __shared__ ushort_t stNV01[4][GEPW][132];      // 16.5 KiB (264B rows: bank spread)
    __shared__ ushort_t stNV2[4][GEPW / 2][132];   // 8.25 KiB
    __shared__ float    relL[4][64];               // 1 KiB: rel rows for the 16-edge group
    int tid = threadIdx.x;
    for (int i = tid; i < 12 * 2 * 64; i += 256) {
        int t  = i >> 7;          // /128
        int kk = (i >> 6) & 1;
        int l  = i & 63;
        int k0 = kk * 32 + (l >> 4) * 8;
        int col = t * 16 + (l & 15);
        #pragma unroll
        for (int jp = 0; jp < 4; ++jp) {
            float a = Ws2[(size_t)(k0 + 2 * jp) * 192 + col];
            float b = Ws2[(size_t)(k0 + 2 * jp + 1) * 192 + col];
            w2frag[i * 4 + jp] = f32_to_bf16_rne(a) | (f32_to_bf16_rne(b) << 16);
        }
    }
    __syncthreads();
    int wave = RFL(tid >> 6);
    int lane = tid & 63;
    float b1 = bs1[lane];
    float b2v_t[4], b2e_t[4], b2s_t[4];
    #pragma unroll
    for (int t = 0; t < 4; ++t) {
        b2v_t[t] = bs2[t * 16 + (lane & 15)];
        b2e_t[t] = bs2[64 + t * 16 + (lane & 15)];
        b2s_t[t] = bs2[128 + t * 16 + (lane & 15)];
    }

    long nG = ((long)E + GEPW - 1) / GEPW;
    for (long g = (long)blockIdx.x * 4 + wave; g < nG; g += (long)gridDim.x * 4) {
        long e0b = g * GEPW;
        int i0a[GEPW], i1a[GEPW];
        #pragma unroll
        for (int e = 0; e < GEPW; ++e) {
            long eid = e0b + e; if (eid >= E) eid = E - 1;
            int2 p = ((const int2*)eidx)[eid];
            i0a[e] = RFL(p.x);
            i1a[e] = RFL(p.y);
        }
        // ---- staging: 41 async LDS loads, ~10.25 KB in flight
        #pragma unroll
        for (int e = 0; e < GEPW; ++e) {
            const char* srcAB = (lane < 32)
                ? ((const char*)Abf + (size_t)i0a[e] * 128 + lane * 4)
                : ((const char*)Bbf + (size_t)i1a[e] * 128 + (lane - 32) * 4);
            gload_lds4(srcAB, &stAB[wave][e][0]);
            gload_lds4((const char*)nvbf + (size_t)i1a[e] * 384 + lane * 4, &stNV01[wave][e][0]);
        }
        #pragma unroll
        for (int p2 = 0; p2 < GEPW / 2; ++p2) {
            const char* src2 = (lane < 32)
                ? ((const char*)nvbf + (size_t)i1a[2 * p2] * 384 + 256 + lane * 4)
                : ((const char*)nvbf + (size_t)i1a[2 * p2 + 1] * 384 + 256 + (lane - 32) * 4);
            gload_lds4(src2, &stNV2[wave][p2][0]);
        }
        gload_lds4((const char*)relg + e0b * 12 + lane * 4, &relL[wave][0]);
        asm volatile("s_waitcnt vmcnt(0)" ::: "memory");
        __builtin_amdgcn_sched_barrier(0);
        // ---- h phase: read A,B bf16, write h f32 XOR-swizzled over the same row
        #pragma unroll
        for (int e = 0; e < GEPW; ++e) {
            float a = bf16_to_f32(stAB[wave][e][lane]);
            float b = bf16_to_f32(stAB[wave][e][64 + lane]);
            float h = silu_f(a + b + b1);
            *(float*)((char*)&stAB[wave][e][0] + ((lane * 4) ^ ((e & 7) << 5))) = h;
        }
        __builtin_amdgcn_sched_barrier(0);
        // ---- MFMA: G[16x192] = H[16x64] @ Ws2[64x192]
        f32x4 acc[12];
        f32x4 zz = {0.f, 0.f, 0.f, 0.f};
        #pragma unroll
        for (int t = 0; t < 12; ++t) acc[t] = zz;
        int row = lane & 15;
        #pragma unroll
        for (int kk = 0; kk < 2; ++kk) {
            int coff = (kk * 128 + ((lane >> 4) * 32)) ^ ((row & 7) << 5);
            const char* hp = (const char*)&stAB[wave][row][0] + coff;
            float4 lo = *(const float4*)hp;
            float4 hi = *(const float4*)(hp + 16);
            unsigned a0, a1, a2, a3;
            asm("v_cvt_pk_bf16_f32 %0, %1, %2" : "=v"(a0) : "v"(lo.x), "v"(lo.y));
            asm("v_cvt_pk_bf16_f32 %0, %1, %2" : "=v"(a1) : "v"(lo.z), "v"(lo.w));
            asm("v_cvt_pk_bf16_f32 %0, %1, %2" : "=v"(a2) : "v"(hi.x), "v"(hi.y));
            asm("v_cvt_pk_bf16_f32 %0, %1, %2" : "=v"(a3) : "v"(hi.z), "v"(hi.w));
            union { unsigned u[4]; bf16x8 v; } af;
            af.u[0] = a0; af.u[1] = a1; af.u[2] = a2; af.u[3] = a3;
            #pragma unroll
            for (int t = 0; t < 12; ++t) {
                bf16x8 bf = *(const bf16x8*)&w2frag[((t * 2 + kk) * 64 + lane) * 4];
                acc[t] = __builtin_amdgcn_mfma_f32_16x16x32_bf16(af.v, bf, acc[t], 0, 0, 0);
            }
        }
        // ---- scatter straight from fragments: lane holds edges (lane>>4)*4+rg, dims t*16+(lane&15)
        int vi_all = 0;
        #pragma unroll
        for (int e = 0; e < GEPW; ++e) vi_all = (lane == e) ? i0a[e] : vi_all;
        int eLane0 = (lane >> 4) * 4;
        #pragma unroll
        for (int rg = 0; rg < 4; ++rg) {
            int e = eLane0 + rg;
            int i0 = __builtin_amdgcn_ds_bpermute(e * 4, vi_all);
            bool ok = (e0b + e) < E;
            float r0v = relL[wave][e * 3 + 0];
            float r1v = relL[wave][e * 3 + 1];
            float r2v = relL[wave][e * 3 + 2];
            #pragma unroll
            for (int t = 0; t < 4; ++t) {
                int dim = t * 16 + (lane & 15);
                float gv = acc[t][rg]     + b2v_t[t];
                float ge = acc[4 + t][rg] + b2e_t[t];
                float ss = acc[8 + t][rg] + b2s_t[t];
                float v0 = bf16_to_f32(stNV01[wave][e][dim]);
                float v1 = bf16_to_f32(stNV01[wave][e][64 + dim]);
                float v2 = bf16_to_f32(stNV2[wave][e >> 1][(e & 1) * 64 + dim]);
                if (ok) {
                    unsafeAtomicAdd(&out0[(size_t)(unsigned)i0 * 64u + dim], ss);
                    unsafeAtomicAdd(&out2[((size_t)(unsigned)i0 * 3u + 0) * 64u + dim], gv * v0 + ge * r0v);
                    unsafeAtomicAdd(&out2[((size_t)(unsigned)i0 * 3u + 1) * 64u + dim], gv * v1 + ge * r1v);
                    unsafeAtomicAdd(&out2[((size_t)(unsigned)i0 * 3u + 2) * 64u + dim], gv * v2 + ge * r2v);
                }
            }
        }
    }
}

// ---------------- Kernel 3: triplets — async LDS staging, TPW=4, f32
#define TPW 4
__global__ __launch_bounds__(256) void triplet_kernel(
    const float* __restrict__ C, const float* __restrict__ Dm,
    const float* __restrict__ pos, const int* __restrict__ tidx,
    const float* __restrict__ bc1, const float* __restrict__ Wc2, const float* __restrict__ bc2,
    float* __restrict__ out1, int T)
{
    __shared__ float wT[64 * 64];
    __shared__ float stC[4][TPW][64];
    __shared__ float stD[4][TPW][3][64];
    int tid = threadIdx.x;
    for (int i = tid; i < 64 * 64 / 4; i += 256)
        ((float4*)wT)[i] = ((const float4*)Wc2)[i];
    __syncthreads();
    int wave = RFL(tid >> 6);
    int lane = tid & 63;
    float b1 = bc1[lane];
    float b2 = bc2[lane] * 3.0f;
    for (long bb = (long)blockIdx.x * (4 * TPW); bb < T; bb += (long)gridDim.x * (4 * TPW)) {
        long t0 = bb + wave * TPW;
        int ib[TPW], it1[TPW], it2[TPW], it3[TPW];
        #pragma unroll
        for (int e = 0; e < TPW; ++e) {
            long t = t0 + e;
            int b = 0, t1 = 0, t2 = 0, t3 = 0;
            if (t < T) { int4 q = ((const int4*)tidx)[t]; b = q.x; t1 = q.y; t2 = q.z; t3 = q.w; }
            ib[e]  = RFL(b);
            it1[e] = RFL(t1);
            it2[e] = RFL(t2);
            it3[e] = RFL(t3);
        }
        #pragma unroll
        for (int e = 0; e < TPW; ++e) {
            gload_lds4(C  + (size_t)ib[e]  * DD + lane, &stC[wave][e][0]);
            gload_lds4(Dm + (size_t)it1[e] * DD + lane, &stD[wave][e][0][0]);
            gload_lds4(Dm + (size_t)it2[e] * DD + lane, &stD[wave][e][1][0]);
            gload_lds4(Dm + (size_t)it3[e] * DD + lane, &stD[wave][e][2][0]);
        }
        asm volatile("s_waitcnt vmcnt(0)" ::: "memory");
        float inv[TPW];
        #pragma unroll
        for (int e = 0; e < TPW; ++e) {
            float hb = stC[wave][e][lane] + b1;
            float h = silu_f(hb + stD[wave][e][0][lane])
                    + silu_f(hb + stD[wave][e][1][lane])
                    + silu_f(hb + stD[wave][e][2][lane]);
            stC[wave][e][lane] = h;
            int b = ib[e], t1 = it1[e], t2 = it2[e], t3 = it3[e];
            double pbx = pos[(size_t)b * 3], pby = pos[(size_t)b * 3 + 1], pbz = pos[(size_t)b * 3 + 2];
            double r1x = pbx - pos[(size_t)t1 * 3], r1y = pby - pos[(size_t)t1 * 3 + 1], r1z = pbz - pos[(size_t)t1 * 3 + 2];
            double r2x = pbx - pos[(size_t)t2 * 3], r2y = pby - pos[(size_t)t2 * 3 + 1], r2z = pbz - pos[(size_t)t2 * 3 + 2];
            double r3x = pbx - pos[(size_t)t3 * 3], r3y = pby - pos[(size_t)t3 * 3 + 1], r3z = pbz - pos[(size_t)t3 * 3 + 2];
            double cx = r2y * r3z - r2z * r3y;
            double cy = r2z * r3x - r2x * r3z;
            double cz = r2x * r3y - r2y * r3x;
            double stp = r1x * cx + r1y * cy + r1z * cz;
            inv[e] = (float)(1.0 / (stp + 0.01));
        }
        float acc[TPW];
        #pragma unroll
        for (int e = 0; e < TPW; ++e) acc[e] = 0.f;
        for (int k4 = 0; k4 < 64; k4 += 4) {
            float4 hk[TPW];
            #pragma unroll
            for (int e = 0; e < TPW; ++e) hk[e] = *(const float4*)&stC[wave][e][k4];
            #pragma unroll
            for (int kk = 0; kk < 4; ++kk) {
                float wk = wT[(k4 + kk) * 64 + lane];
                #pragma unroll
                for (int e = 0; e < TPW; ++e) acc[e] += (&hk[e].x)[kk] * wk;
            }
        }
        #pragma unroll
        for (int e = 0; e < TPW; ++e) {
            long t = t0 + e;
            if (t >= T) break;
            unsafeAtomicAdd(&out1[(size_t)ib[e] * DD + lane], (acc[e] + b2) * inv[e]);
        }
    }
}

extern "C" void kernel_launch(void* const* d_in, const int* in_sizes, int n_in,
                              void* d_out, int out_size, void* d_ws, size_t ws_size,
                              hipStream_t stream)
{
    const float* ns  = (const float*)d_in[0];
    const float* nc  = (const float*)d_in[1];
    const float* nv  = (const float*)d_in[2];
    const float* pos = (const float*)d_in[3];
    const int* eidx  = (const int*)d_in[4];
    const int* tidx  = (const int*)d_in[5];
    const float* Ws1 = (const float*)d_in[6];
    const float* bs1 = (const float*)d_in[7];
    const float* Ws2 = (const float*)d_in[8];
    const float* bs2 = (const float*)d_in[9];
    const float* Wc1 = (const float*)d_in[10];
    const float* bc1 = (const float*)d_in[11];
    const float* Wc2 = (const float*)d_in[12];
    const float* bc2 = (const float*)d_in[13];
    const float* WV  = (const float*)d_in[14];
    const float* bV  = (const float*)d_in[15];

    int N = in_sizes[0] / 64;
    int E = in_sizes[4] / 2;
    int T = in_sizes[5] / 4;

    float* out0 = (float*)d_out;
    float* out1 = out0 + (size_t)N * 64;
    float* out2 = out1 + (size_t)N * 64;

    // workspace: C, Dm, relg (f32), then bf16 arrays
    float* C    = (float*)d_ws;
    float* Dm   = C + (size_t)N * 64;
    float* relg = Dm + (size_t)N * 64;                 // E*3 + 64 floats (padded)
    ushort_t* Abf  = (ushort_t*)(relg + (size_t)E * 3 + 64);
    ushort_t* Bbf  = Abf + (size_t)N * 64;
    ushort_t* nvbf = Bbf + (size_t)N * 64;

    rel_kernel<<<(E + 255) / 256, 256, 0, stream>>>(eidx, pos, relg, E);
    node_transform_kernel<<<2048, 256, 0, stream>>>(ns, nc, Ws1, Wc1, Abf, Bbf, C, Dm, out1, N);
    node_vector_kernel<<<2048, 256, 0, stream>>>(ns, nv, WV, bV, out0, out2, nvbf, N);
    edge_kernel<<<4096, 256, 0, stream>>>(Abf, Bbf, nvbf, relg, eidx, bs1, Ws2, bs2, out0, out2, E);
    triplet_kernel<<<4096, 256, 0, stream>>>(C, Dm, pos, tidx, bc1, Wc2, bc2, out1, T);
}